// Round 10
// baseline (132.662 us; speedup 1.0000x reference)
//
#include <hip/hip_runtime.h>

// PostProcessor3D: threshold(>0.9) + 5x5x5 stride-1 maxpool + strict-local-max
// mask on [64,512,512] fp32.
//
// R10: wave-autonomous with NO LDS at all. R9's barrier-free LDS row buffer
// was broken: lanes read other lanes' LDS writes with no fence, and the
// compiler legally reorders provably-distinct-address LDS ops -> scrambled
// W-max. The cross-lane need is only 2 floats from each neighbor quad, so use
// __shfl_up/__shfl_down/__shfl (register cross-lane, well-defined) instead.
//
// Per wave-task (one d-slice, 8-row h-strip, full 512 W), per row-step:
//   - load row r of the 5 D-window slices (2 half-rows/lane = 10 float4),
//     threshold + D-max IN THE LOAD STAGE (keeps live state small), keep
//     middle slice as center row; distance-1 row prefetch (pending regs)
//   - W-max via 12 shuffles + boundary selects (zero pad at w edges)
//   - 5-deep H register ring -> H-max; 3-deep center ring; strict-local-max
//   - nontemporal float4 stores
// Loop fully unrolled -> ring indices compile-time constant (no scratch
// spill, R3 lesson). All branches wave-uniform except the 8 boundary-lane
// selects (cndmask). Zero-padding == reference -inf padding (thresholded
// values >= 0, center always inside its own window).
//
// 4096 tasks = 1024 blocks x 4 waves -> 16 waves/CU (TLP) on top of 160
// B/lane in-flight loads (MLP). d+-1 tasks are 16 blocks apart -> same XCD
// under round-robin dispatch -> D-overlap re-reads hit that XCD's L2.

#define THRESH 0.9f

constexpr int D = 64, H = 512, W = 512;
constexpr int HW = H * W;
constexpr int HS = 8;                     // output rows per wave-task
constexpr int STEPS = HS + 4;             // 12 row-steps (H halo 2+2)

typedef float floatx4 __attribute__((ext_vector_type(4)));

__device__ __forceinline__ float4 thresh4(float4 v) {
    v.x = (v.x > THRESH) ? v.x : 0.f;
    v.y = (v.y > THRESH) ? v.y : 0.f;
    v.z = (v.z > THRESH) ? v.z : 0.f;
    v.w = (v.w > THRESH) ? v.w : 0.f;
    return v;
}

__device__ __forceinline__ float4 max4(float4 a, float4 b) {
    return make_float4(fmaxf(a.x, b.x), fmaxf(a.y, b.y),
                       fmaxf(a.z, b.z), fmaxf(a.w, b.w));
}

// 5-tap sliding max for one output quad. b = own quad (f4..f7 at w=4c..4c+3),
// f2,f3 = prev quad's .z,.w (w=4c-2,4c-1), f8,f9 = next quad's .x,.y
// (w=4c+4,4c+5). out[j] = max over [4c+j-2, 4c+j+2].
__device__ __forceinline__ float4 wmax5s(float f2, float f3, float4 b,
                                         float f8, float f9) {
    const float f4 = b.x, f5 = b.y, f6 = b.z, f7 = b.w;
    const float m45 = fmaxf(f4, f5);
    const float m56 = fmaxf(f5, f6);
    const float m345 = fmaxf(f3, m45);
    const float m456 = fmaxf(f4, m56);
    const float m567 = fmaxf(m56, f7);
    const float m678 = fmaxf(fmaxf(f6, f7), f8);
    float4 r;
    r.x = fmaxf(fmaxf(f2, f6), m345);
    r.y = fmaxf(fmaxf(f3, f7), m456);
    r.z = fmaxf(fmaxf(f4, f8), m567);
    r.w = fmaxf(fmaxf(f5, f9), m678);
    return r;
}

__global__ __launch_bounds__(256)
void peak3d_kernel(const float* __restrict__ in, float* __restrict__ out) {
    const int lane = threadIdx.x & 63;
    const int wv   = threadIdx.x >> 6;

    const int task = blockIdx.x * 4 + wv;     // 0..4095
    const int d    = task >> 6;               // 0..63
    const int h0   = (task & 63) * HS;        // 0..504

    const float4 zero4 = make_float4(0.f, 0.f, 0.f, 0.f);

    // D-window slice bases (wave-uniform -> SGPRs, scalar branches).
    const float* pj[5];
    bool dv[5];
#pragma unroll
    for (int j = 0; j < 5; ++j) {
        const int dz = d - 2 + j;
        dv[j] = (dz >= 0 && dz < D);
        pj[j] = in + (size_t)(dv[j] ? dz : 0) * HW;
    }

    // Load row r: threshold + D-max on the fly; capture middle slice (center).
    auto loadRow = [&](int r, float4& zA, float4& zB, float4& cA, float4& cB) {
        zA = zero4; zB = zero4; cA = zero4; cB = zero4;
        if (r >= 0 && r < H) {                // wave-uniform
#pragma unroll
            for (int j = 0; j < 5; ++j) {
                if (dv[j]) {                  // wave-uniform
                    const float* p = pj[j] + (size_t)r * W + 4 * lane;
                    const float4 a = thresh4(*reinterpret_cast<const float4*>(p));
                    const float4 b = thresh4(*reinterpret_cast<const float4*>(p + 256));
                    zA = max4(zA, a); zB = max4(zB, b);
                    if (j == 2) { cA = a; cB = b; }
                }
            }
        }
    };

    float4 pzA, pzB, pcA, pcB;                // pending (prefetched) row
    loadRow(h0 - 2, pzA, pzB, pcA, pcB);      // prime row r_0 = h0-2

    float4 wza[5], wzb[5];                    // H-ring of W-maxed D-max rows
    float4 cena[3], cenb[3];                  // center-value ring
#pragma unroll
    for (int k = 0; k < 5; ++k) { wza[k] = zero4; wzb[k] = zero4; }
#pragma unroll
    for (int k = 0; k < 3; ++k) { cena[k] = zero4; cenb[k] = zero4; }

#pragma unroll
    for (int t = 0; t < STEPS; ++t) {         // fully unrolled
        // consume pending row t, then prefetch row t+1 into pending
        const float4 za = pzA, zb = pzB;
        cena[t % 3] = pcA;                    // row r_t center values
        cenb[t % 3] = pcB;
        if (t + 1 < STEPS) loadRow(h0 - 1 + t, pzA, pzB, pcA, pcB);

        // ---- cross-lane W-max (no LDS) ----
        // half a: quads 0..63 (quad c = lane); half b: quads 64..127.
        float f2a = __shfl_up(za.z, 1);
        float f3a = __shfl_up(za.w, 1);
        float f8a = __shfl_down(za.x, 1);
        float f9a = __shfl_down(za.y, 1);
        float f2b = __shfl_up(zb.z, 1);
        float f3b = __shfl_up(zb.w, 1);
        float f8b = __shfl_down(zb.x, 1);
        float f9b = __shfl_down(zb.y, 1);
        const float zb0x  = __shfl(zb.x, 0);      // quad 64 .x (for a, lane 63)
        const float zb0y  = __shfl(zb.y, 0);
        const float za63z = __shfl(za.z, 63);     // quad 63 .z (for b, lane 0)
        const float za63w = __shfl(za.w, 63);
        if (lane == 0)  { f2a = 0.f; f3a = 0.f; f2b = za63z; f3b = za63w; }
        if (lane == 63) { f8a = zb0x; f9a = zb0y; f8b = 0.f; f9b = 0.f; }

        wza[t % 5] = wmax5s(f2a, f3a, za, f8a, f9a);
        wzb[t % 5] = wmax5s(f2b, f3b, zb, f8b, f9b);

        // ---- H-max + strict-local-max + store (rows r_{t-4}..r_t) ----
        if (t >= 4) {
            const int hout = h0 + t - 4;          // center row r_{t-2}
            const float4 mpa = max4(max4(max4(wza[0], wza[1]),
                                         max4(wza[2], wza[3])), wza[4]);
            const float4 mpb = max4(max4(max4(wzb[0], wzb[1]),
                                         max4(wzb[2], wzb[3])), wzb[4]);
            const float4 tca = cena[(t + 1) % 3]; // written at step t-2
            const float4 tcb = cenb[(t + 1) % 3];
            floatx4 ra, rc;
            ra.x = (mpa.x > 0.f && mpa.x == tca.x) ? mpa.x : 0.f;
            ra.y = (mpa.y > 0.f && mpa.y == tca.y) ? mpa.y : 0.f;
            ra.z = (mpa.z > 0.f && mpa.z == tca.z) ? mpa.z : 0.f;
            ra.w = (mpa.w > 0.f && mpa.w == tca.w) ? mpa.w : 0.f;
            rc.x = (mpb.x > 0.f && mpb.x == tcb.x) ? mpb.x : 0.f;
            rc.y = (mpb.y > 0.f && mpb.y == tcb.y) ? mpb.y : 0.f;
            rc.z = (mpb.z > 0.f && mpb.z == tcb.z) ? mpb.z : 0.f;
            rc.w = (mpb.w > 0.f && mpb.w == tcb.w) ? mpb.w : 0.f;
            float* o = out + (size_t)d * HW + (size_t)hout * W + 4 * lane;
            __builtin_nontemporal_store(ra, reinterpret_cast<floatx4*>(o));
            __builtin_nontemporal_store(rc, reinterpret_cast<floatx4*>(o + 256));
        }
    }
}

extern "C" void kernel_launch(void* const* d_in, const int* in_sizes, int n_in,
                              void* d_out, int out_size, void* d_ws, size_t ws_size,
                              hipStream_t stream) {
    const float* in = (const float*)d_in[0];
    float* out = (float*)d_out;
    dim3 grid(1024, 1, 1);                    // 4096 wave-tasks / 4 waves/block
    dim3 block(256, 1, 1);
    hipLaunchKernelGGL(peak3d_kernel, grid, block, 0, stream, in, out);
}

// Round 11
// 116.601 us; speedup vs baseline: 1.1377x; 1.1377x over previous
//
#include <hip/hip_runtime.h>

// PostProcessor3D: threshold(>0.9) + 5x5x5 stride-1 maxpool + strict-local-max
// mask on [64,512,512] fp32.
//
// R11: lighten the per-slice convoy (all R2-R10 variants converge to ~52 us
// with no pipe >40% -- the limiter is the per-iteration latency chain, not
// BW/occupancy/barrier-flavor).
//  (a) RAW-MAX TRICK: thresh commutes with max, and the center is always in
//      its own window, so out = (c>0.9 && c==rawmax(window)) ? c : 0.
//      -> NO thresholding anywhere in the hot loop (stage raw, compare raw).
//  (b) ONE barrier + ONE LDS round-trip per slice: consume phase does H-max
//      directly (5 ds_read_b128, rows ty..ty+4 at col tx+1) + halo H-max
//      (5 reads at col 0 for tx==0 / col 17 for tx==15), then W-max via 4
//      shuffles on the H-maxed quads. No second LDS array, no W-stage.
//  (c) raw[] double-buffered; no-drain barrier (lgkmcnt only, global
//      prefetch loads stay in flight; reg deps enforced by compiler vmcnt).
//      Hazards: stage(t)->consume(t): B(t). consume reads raw[t&1]@t vs
//      stage rewrite @t+2: B(t+1) between. One barrier/iter is sufficient.
//  (d) dist-2 register prefetch (R8 machinery, proven).
// Loop fully unrolled (NS=20) -> ring/slot indices compile-time constants
// (no scratch spill; R3 lesson). Zero-padding valid: raw values >= 0.
//
// Tile: W=64 x H=16, DCHUNK=16 -> grid 8x32x4 = 1024 blocks, 4/CU.

#define THRESH 0.9f

constexpr int D = 64, H = 512, W = 512;
constexpr int HW = H * W;
constexpr int TW = 64;                    // tile width in floats
constexpr int TH = 16;                    // tile height
constexpr int DCHUNK = 16;                // depth outputs per block
constexpr int HALO = 2;
constexpr int LROWS = TH + 2 * HALO;      // 20 staged rows
constexpr int RAWQ  = TW / 4 + 2;         // 18 quads/row: [w0-4, w0+68)
constexpr int RAW_S = RAWQ + 1;           // 19: de-phase rows
constexpr int NS = DCHUNK + 2 * HALO;     // 20 slices per block

typedef float floatx4 __attribute__((ext_vector_type(4)));

__device__ __forceinline__ void barrier_no_drain() {
    asm volatile("s_waitcnt lgkmcnt(0)\n\ts_barrier" ::: "memory");
}

__device__ __forceinline__ float4 max4(float4 a, float4 b) {
    return make_float4(fmaxf(a.x, b.x), fmaxf(a.y, b.y),
                       fmaxf(a.z, b.z), fmaxf(a.w, b.w));
}

// 5-tap sliding max for one quad. b = own (f4..f7), f2,f3 = left neighbor's
// .z,.w; f8,f9 = right neighbor's .x,.y. out[j] = max over [4c+j-2, 4c+j+2].
__device__ __forceinline__ float4 wmax5s(float f2, float f3, float4 b,
                                         float f8, float f9) {
    const float f4 = b.x, f5 = b.y, f6 = b.z, f7 = b.w;
    const float m45 = fmaxf(f4, f5);
    const float m56 = fmaxf(f5, f6);
    const float m345 = fmaxf(f3, m45);
    const float m456 = fmaxf(f4, m56);
    const float m567 = fmaxf(m56, f7);
    const float m678 = fmaxf(fmaxf(f6, f7), f8);
    float4 r;
    r.x = fmaxf(fmaxf(f2, f6), m345);
    r.y = fmaxf(fmaxf(f3, f7), m456);
    r.z = fmaxf(fmaxf(f4, f8), m567);
    r.w = fmaxf(fmaxf(f5, f9), m678);
    return r;
}

__global__ __launch_bounds__(256)
void peak3d_kernel(const float* __restrict__ in, float* __restrict__ out) {
    __shared__ float4 raw[2][LROWS * RAW_S];  // 2 x 380 quads = 12160 B

    const int tx = threadIdx.x;               // 0..15 (quad col)
    const int ty = threadIdx.y;               // 0..15 (row)
    const int tid = ty * 16 + tx;

    const int w0 = blockIdx.x * TW;
    const int h0 = blockIdx.y * TH;
    const int d0 = blockIdx.z * DCHUNK;

    // Staging map: 20 rows x 18 quads = 360 quads, <=2 per thread.
    const int q0 = tid;
    const int q1 = tid + 256;
    const int r0 = q0 / RAWQ, c0 = q0 % RAWQ;
    const int r1 = q1 / RAWQ, c1 = q1 % RAWQ;
    const int lds0 = r0 * RAW_S + c0;
    const int lds1 = r1 * RAW_S + c1;
    const int gh0 = h0 + r0 - HALO, gw0 = w0 + 4 * c0 - 4;
    const int gh1 = h0 + r1 - HALO, gw1 = w0 + 4 * c1 - 4;
    const bool has1 = (q1 < LROWS * RAWQ);
    const bool ib0 = (gh0 >= 0 && gh0 < H && gw0 >= 0 && gw0 < W);
    const bool ib1 = has1 && (gh1 >= 0 && gh1 < H && gw1 >= 0 && gw1 < W);
    const size_t off0 = ib0 ? ((size_t)gh0 * W + gw0) : 0;
    const size_t off1 = ib1 ? ((size_t)gh1 * W + gw1) : 0;

    const float4 zero4 = make_float4(0.f, 0.f, 0.f, 0.f);
    float4 win[5], cen[5];
#pragma unroll
    for (int k = 0; k < 5; ++k) { win[k] = zero4; cen[k] = zero4; }

    auto loadSlice = [&](int dd, float4& a, float4& b) {  // RAW (no thresh)
        a = zero4; b = zero4;
        if (dd >= 0 && dd < D) {
            const size_t base = (size_t)dd * HW;
            if (ib0) a = *reinterpret_cast<const float4*>(in + base + off0);
            if (ib1) b = *reinterpret_cast<const float4*>(in + base + off1);
        }
    };

    // Distance-2 register prefetch.
    float4 pfa[2], pfb[2];
    loadSlice(d0 - HALO + 0, pfa[0], pfb[0]);
    loadSlice(d0 - HALO + 1, pfa[1], pfb[1]);

    // Consume-phase LDS column for the halo H-max (left edge / right edge).
    const int hcol = (tx == 0) ? 0 : (RAWQ - 1);   // 0 or 17

#pragma unroll
    for (int t = 0; t < NS; ++t) {            // fully unrolled: t constant
        const int buf = t & 1;

        // ---- stage slice t (raw values), refill slot with slice t+2 ----
        raw[buf][lds0] = pfa[buf];
        if (has1) raw[buf][lds1] = pfb[buf];
        if (t + 2 < NS) loadSlice(d0 - HALO + t + 2, pfa[buf], pfb[buf]);

        barrier_no_drain();                   // the only barrier per slice

        // ---- consume: H-max (5 rows) + halo + W-max via shuffles ----
        const float4* bp = &raw[buf][0];
        const float4 r0q = bp[(ty + 0) * RAW_S + (tx + 1)];
        const float4 r1q = bp[(ty + 1) * RAW_S + (tx + 1)];
        const float4 r2q = bp[(ty + 2) * RAW_S + (tx + 1)];  // center row
        const float4 r3q = bp[(ty + 3) * RAW_S + (tx + 1)];
        const float4 r4q = bp[(ty + 4) * RAW_S + (tx + 1)];
        const float4 hv = max4(max4(max4(r0q, r1q), max4(r3q, r4q)), r2q);

        const float4 e0 = bp[(ty + 0) * RAW_S + hcol];
        const float4 e1 = bp[(ty + 1) * RAW_S + hcol];
        const float4 e2 = bp[(ty + 2) * RAW_S + hcol];
        const float4 e3 = bp[(ty + 3) * RAW_S + hcol];
        const float4 e4 = bp[(ty + 4) * RAW_S + hcol];
        const float4 hq = max4(max4(max4(e0, e1), max4(e3, e4)), e2);

        float f2 = __shfl_up(hv.z, 1);        // left neighbor (same row-group)
        float f3 = __shfl_up(hv.w, 1);
        float f8 = __shfl_down(hv.x, 1);      // right neighbor
        float f9 = __shfl_down(hv.y, 1);
        if (tx == 0)  { f2 = hq.z; f3 = hq.w; }   // left halo quad (col 0)
        if (tx == 15) { f8 = hq.x; f9 = hq.y; }   // right halo quad (col 17)

        win[t % 5] = wmax5s(f2, f3, hv, f8, f9);  // HW-max, slice t
        cen[t % 5] = r2q;                          // raw center row, slice t

        // ---- D-max + strict-local-max + store (slices t-4..t) ----
        if (t >= 4) {
            const int dout = d0 + (t - 4);    // = (d0-2+t) - 2, window center
            const float4 mp = max4(max4(max4(win[0], win[1]),
                                        max4(win[2], win[3])), win[4]);
            const float4 c = cen[(t + 3) % 5];     // written at iter t-2
            floatx4 res;
            res.x = (c.x > THRESH && mp.x == c.x) ? c.x : 0.f;
            res.y = (c.y > THRESH && mp.y == c.y) ? c.y : 0.f;
            res.z = (c.z > THRESH && mp.z == c.z) ? c.z : 0.f;
            res.w = (c.w > THRESH && mp.w == c.w) ? c.w : 0.f;
            floatx4* op = reinterpret_cast<floatx4*>(
                out + (size_t)dout * HW + (size_t)(h0 + ty) * W + (w0 + 4 * tx));
            __builtin_nontemporal_store(res, op);
        }
    }
}

extern "C" void kernel_launch(void* const* d_in, const int* in_sizes, int n_in,
                              void* d_out, int out_size, void* d_ws, size_t ws_size,
                              hipStream_t stream) {
    const float* in = (const float*)d_in[0];
    float* out = (float*)d_out;
    dim3 grid(W / TW, H / TH, D / DCHUNK);    // 8 x 32 x 4 = 1024 blocks
    dim3 block(16, 16, 1);
    hipLaunchKernelGGL(peak3d_kernel, grid, block, 0, stream, in, out);
}